// Round 3
// baseline (766.004 us; speedup 1.0000x reference)
//
#include <hip/hip_runtime.h>
#include <math.h>

// Dims
#define D_    2048
#define E_    64
#define ROWS  32768            // G*T = 8*4096
#define BM    256              // rows per block tile
#define BK    32               // K slice per iteration
#define KSL   4                // K-split factor
#define KD    (D_/KSL)         // 512 K-depth per block
#define NIT   (KD/BK)          // 16 iterations
#define XS    260              // padded LDS stride for x tile (16B-aligned rows of b128 reads)
#define WSTR  68               // padded LDS stride for w tile

// ---------------- GEMM partial kernel: lacc[row][e] += sum_k x[row,k]*w[e,k] ----------------
__global__ __launch_bounds__(256, 2) void router_gemm(
    const float* __restrict__ tok,   // [ROWS, D]
    const float* __restrict__ noi,   // [ROWS, D]
    const float* __restrict__ wgt,   // [E, D]
    float* __restrict__ lacc,        // [ROWS, E] zero-initialized accumulator (= masked output slot)
    float* __restrict__ absrow)      // [ROWS]    zero-initialized |x| row sums
{
    __shared__ float xs[BK][XS];     // x tile transposed: xs[k][row]
    __shared__ float wsh[BK][WSTR];  // w tile transposed: wsh[k][e]

    const int tid  = threadIdx.x;
    const int lane = tid & 63;
    const int wv   = tid >> 6;
    const int rowblk = (int)blockIdx.x >> 2;
    const int ks     = (int)blockIdx.x & 3;
    const size_t row0 = (size_t)rowblk * BM;
    const int k0 = ks * KD;

    // x loader: 8 passes; row = p*32 + wv*8 + (lane>>3); float4 at k-offset (lane&7)*4
    // (8 consecutive lanes read 128B contiguous of one row -> coalesced)
    const int lr  = wv*8 + (lane>>3);
    const int lko = (lane&7)*4;
    const float* tptr = tok + (row0 + (size_t)lr)*D_ + (k0 + lko);
    const float* nptr = noi + (row0 + (size_t)lr)*D_ + (k0 + lko);

    // w loader: e = tid>>2, 8 floats at k-offset (tid&3)*8 (4 lanes = 128B of one e-row)
    const int we  = tid >> 2;
    const int wko = (tid & 3) * 8;
    const float* wptr = wgt + (size_t)we*D_ + (k0 + wko);

    // FMA mapping: 8x8 per-thread tile
    const int ty = tid >> 3;   // 0..31 -> rows ty*8 .. ty*8+7
    const int tx = tid & 7;    // 0..7  -> experts tx*8 .. tx*8+7

    float acc[8][8];
#pragma unroll
    for (int i = 0; i < 8; ++i)
#pragma unroll
        for (int j = 0; j < 8; ++j) acc[i][j] = 0.f;
    float absp[8];
#pragma unroll
    for (int p = 0; p < 8; ++p) absp[p] = 0.f;

    // ---- register prefetch of tile 0 (raw; jitter applied at store time) ----
    float4 ta[8], na[8], wa, wb;
#pragma unroll
    for (int p = 0; p < 8; ++p) {
        ta[p] = *(const float4*)(tptr + (size_t)p*32*D_);
        na[p] = *(const float4*)(nptr + (size_t)p*32*D_);
    }
    wa = *(const float4*)(wptr);
    wb = *(const float4*)(wptr + 4);

    for (int it = 0; it < NIT; ++it) {
        __syncthreads();    // previous FMA phase done before overwriting LDS

        // jitter + transposed store + |x| accumulation
#pragma unroll
        for (int p = 0; p < 8; ++p) {
            const int row = p*32 + lr;
            const float x0 = ta[p].x * (0.99f + 0.02f * na[p].x);
            const float x1 = ta[p].y * (0.99f + 0.02f * na[p].y);
            const float x2 = ta[p].z * (0.99f + 0.02f * na[p].z);
            const float x3 = ta[p].w * (0.99f + 0.02f * na[p].w);
            xs[lko+0][row] = x0;
            xs[lko+1][row] = x1;
            xs[lko+2][row] = x2;
            xs[lko+3][row] = x3;
            absp[p] += fabsf(x0) + fabsf(x1) + fabsf(x2) + fabsf(x3);
        }
        {
            const float* w0 = &wa.x;
            const float* w1 = &wb.x;
#pragma unroll
            for (int j = 0; j < 4; ++j) wsh[wko+j][we]   = w0[j];
#pragma unroll
            for (int j = 0; j < 4; ++j) wsh[wko+4+j][we] = w1[j];
        }
        __syncthreads();

        // prefetch next tile (clamped last iter; stores won't re-run so absp stays correct)
        {
            const int itn = (it + 1 < NIT) ? it + 1 : it;
            const float* tp = tptr + itn*BK;
            const float* np = nptr + itn*BK;
            const float* wp = wptr + itn*BK;
#pragma unroll
            for (int p = 0; p < 8; ++p) {
                ta[p] = *(const float4*)(tp + (size_t)p*32*D_);
                na[p] = *(const float4*)(np + (size_t)p*32*D_);
            }
            wa = *(const float4*)(wp);
            wb = *(const float4*)(wp + 4);
        }

        // FMA over the LDS tile
#pragma unroll 8
        for (int k = 0; k < BK; ++k) {
            float4 a0 = *(const float4*)&xs[k][ty*8];
            float4 a1 = *(const float4*)&xs[k][ty*8+4];
            float4 b0 = *(const float4*)&wsh[k][tx*8];
            float4 b1 = *(const float4*)&wsh[k][tx*8+4];
            float av[8] = {a0.x,a0.y,a0.z,a0.w,a1.x,a1.y,a1.z,a1.w};
            float bv[8] = {b0.x,b0.y,b0.z,b0.w,b1.x,b1.y,b1.z,b1.w};
#pragma unroll
            for (int i = 0; i < 8; ++i)
#pragma unroll
                for (int j = 0; j < 8; ++j)
                    acc[i][j] = fmaf(av[i], bv[j], acc[i][j]);
        }
    }

    // ---- accumulate partial logits (4 k-slices collide -> atomic) ----
#pragma unroll
    for (int i = 0; i < 8; ++i) {
        float* base = lacc + (row0 + (size_t)(ty*8 + i))*E_ + tx*8;
#pragma unroll
        for (int j = 0; j < 8; ++j) atomicAdd(base + j, acc[i][j]);
    }

    // ---- per-row |x| partials: reduce 8-lane group, one atomic per row per block ----
#pragma unroll
    for (int p = 0; p < 8; ++p) {
        float v = absp[p];
        v += __shfl_xor(v, 1);
        v += __shfl_xor(v, 2);
        v += __shfl_xor(v, 4);
        if ((lane & 7) == 0) atomicAdd(&absrow[row0 + (size_t)(p*32 + lr)], v);
    }
}

// ---------------- epilogue: bias + softmax + mask + z-loss ----------------
__global__ __launch_bounds__(256) void router_epi(
    const float* __restrict__ bias,
    float* __restrict__ probs,
    float* __restrict__ lacc,        // in: summed logits (pre-bias); out: masked logits
    const float* __restrict__ absrow,
    float* __restrict__ zloss)
{
    __shared__ float zred[4];
    const int tid = threadIdx.x;
    const int lane = tid & 63;
    const int wv = tid >> 6;
    const int r  = tid >> 4;         // 0..15 row within block
    const int tx = tid & 15;         // 16 lanes per row, 4 experts each
    const size_t row = (size_t)blockIdx.x*16 + r;

    float4 l4 = *(const float4*)&lacc[row*E_ + tx*4];
    float l[4] = { l4.x + bias[tx*4+0], l4.y + bias[tx*4+1],
                   l4.z + bias[tx*4+2], l4.w + bias[tx*4+3] };

    // softmax over 64 experts (16-lane group reduction)
    float m = fmaxf(fmaxf(l[0], l[1]), fmaxf(l[2], l[3]));
    m = fmaxf(m, __shfl_xor(m, 1));
    m = fmaxf(m, __shfl_xor(m, 2));
    m = fmaxf(m, __shfl_xor(m, 4));
    m = fmaxf(m, __shfl_xor(m, 8));
    float e[4]; float s = 0.f;
#pragma unroll
    for (int j = 0; j < 4; ++j) { e[j] = expf(l[j] - m); s += e[j]; }
    s += __shfl_xor(s, 1);
    s += __shfl_xor(s, 2);
    s += __shfl_xor(s, 4);
    s += __shfl_xor(s, 8);
    const float rs = 1.f / s;
    float4 pv = { e[0]*rs, e[1]*rs, e[2]*rs, e[3]*rs };
    *(float4*)(probs + row*E_ + tx*4) = pv;

    // masked logits
    const float msk = (absrow[row] > 0.f) ? 1.f : 0.f;
    float ml[4] = { l[0]*msk, l[1]*msk, l[2]*msk, l[3]*msk };
    float4 mv = { ml[0], ml[1], ml[2], ml[3] };
    *(float4*)(lacc + row*E_ + tx*4) = mv;

    // logsumexp of masked logits -> z partial
    float mm = fmaxf(fmaxf(ml[0], ml[1]), fmaxf(ml[2], ml[3]));
    mm = fmaxf(mm, __shfl_xor(mm, 1));
    mm = fmaxf(mm, __shfl_xor(mm, 2));
    mm = fmaxf(mm, __shfl_xor(mm, 4));
    mm = fmaxf(mm, __shfl_xor(mm, 8));
    float ss = 0.f;
#pragma unroll
    for (int j = 0; j < 4; ++j) ss += expf(ml[j] - mm);
    ss += __shfl_xor(ss, 1);
    ss += __shfl_xor(ss, 2);
    ss += __shfl_xor(ss, 4);
    ss += __shfl_xor(ss, 8);

    float zp = 0.f;
    if (tx == 0) {
        const float lse = mm + logf(ss);
        zp = lse * lse;
    }
    zp += __shfl_xor(zp, 16);
    zp += __shfl_xor(zp, 32);
    if (lane == 0) zred[wv] = zp;
    __syncthreads();
    if (tid == 0)
        atomicAdd(zloss, (zred[0]+zred[1]+zred[2]+zred[3]) * (1.0f/(float)ROWS));
}

extern "C" void kernel_launch(void* const* d_in, const int* in_sizes, int n_in,
                              void* d_out, int out_size, void* d_ws, size_t ws_size,
                              hipStream_t stream) {
    (void)in_sizes; (void)n_in; (void)ws_size; (void)out_size;
    const float* tok  = (const float*)d_in[0];
    const float* noi  = (const float*)d_in[1];
    const float* wgt  = (const float*)d_in[2];
    const float* bias = (const float*)d_in[3];

    float* probs  = (float*)d_out;
    float* lacc   = probs + (size_t)ROWS * E_;     // masked-logits slot doubles as accumulator
    float* zloss  = probs + 2 * (size_t)ROWS * E_;
    float* absrow = (float*)d_ws;                   // 128 KB scratch

    // zero accumulator + zloss (contiguous) and absrow
    hipMemsetAsync(lacc, 0, ((size_t)ROWS * E_ + 1) * sizeof(float), stream);
    hipMemsetAsync(absrow, 0, (size_t)ROWS * sizeof(float), stream);

    router_gemm<<<dim3((ROWS/BM)*KSL), dim3(256), 0, stream>>>(tok, noi, wgt, lacc, absrow);
    router_epi <<<dim3(ROWS/16),       dim3(256), 0, stream>>>(bias, probs, lacc, absrow, zloss);
}